// Round 9
// baseline (417.376 us; speedup 1.0000x reference)
//
#include <hip/hip_runtime.h>

typedef unsigned char u8;
typedef float f32x4 __attribute__((ext_vector_type(4)));
typedef float f32x16 __attribute__((ext_vector_type(16)));

#define LL 4096
#define PSTR 136                        // P row stride (bytes), validated R5/R8 (~0 conflicts)
#define SCALE 16.0f                     // x pre-scale before fp8
#define GSCALE2 (1.44269504f/256.0f)    // undo SCALE^2 AND convert to log2 units
#define NHL2E (-0.721347520444482f)     // -0.5 * log2(e), folded into stored norms
#define FREQC (-0.03597789207803197f)   // -ln(10000)/256

__device__ __forceinline__ long LCAST(uint2 v) { return __builtin_bit_cast(long, v); }

typedef __attribute__((address_space(3))) u8 lds_u8;
typedef __attribute__((address_space(1))) u8 glb_u8;
__device__ __forceinline__ void dma16(const u8* g, u8* l) {
  __builtin_amdgcn_global_load_lds((const glb_u8*)g, (lds_u8*)l, 16, 0, 0);
}

// ---------------- prep1 (R5-R8 validated; sq now stored in -0.5*log2e units) ----------------
// xbf: row r (256 B): 8-B chunk c stored at ((c ^ (r&31))*8).
// xT : d-row (4096 B) split into 32 j-segments of 128 B; chunk c in segment at ((c ^ (d&15))*8).
__global__ __launch_bounds__(256) void prep1(const float* __restrict__ x, u8* __restrict__ xbf,
                                             u8* __restrict__ xT, float* __restrict__ sq) {
  __shared__ u8 T[16 * 264];
  const int blk = blockIdx.x;
  const int b = blk >> 8, r0 = (blk & 255) << 4;
  const int tid = threadIdx.x;
  const long rowbase = (long)(b << 12) + r0;
  const float4* x4 = (const float4*)x + rowbase * 64;
  unsigned* xb4 = (unsigned*)xbf + rowbase * 64;
  #pragma unroll
  for (int i = 0; i < 4; ++i) {
    int idx = i * 256 + tid;
    float4 v = x4[idx];
    float s = v.x * v.x + v.y * v.y + v.z * v.z + v.w * v.w;
    #pragma unroll
    for (int o = 32; o; o >>= 1) s += __shfl_xor(s, o);
    int row = idx >> 6, dw = idx & 63;
    if ((tid & 63) == 0) sq[rowbase + row] = s * NHL2E;
    int pk = __builtin_amdgcn_cvt_pk_fp8_f32(v.x * SCALE, v.y * SCALE, 0, false);
    pk = __builtin_amdgcn_cvt_pk_fp8_f32(v.z * SCALE, v.w * SCALE, pk, true);
    int sdw = (((dw >> 1) ^ ((r0 + row) & 31)) << 1) | (dw & 1);
    xb4[row * 64 + sdw] = (unsigned)pk;
    *(unsigned*)(T + row * 264 + dw * 4) = (unsigned)pk;
  }
  __syncthreads();
  unsigned ob[4];
  #pragma unroll
  for (int jj = 0; jj < 4; ++jj) {
    unsigned b0 = T[(4 * jj + 0) * 264 + tid];
    unsigned b1 = T[(4 * jj + 1) * 264 + tid];
    unsigned b2 = T[(4 * jj + 2) * 264 + tid];
    unsigned b3 = T[(4 * jj + 3) * 264 + tid];
    ob[jj] = b0 | (b1 << 8) | (b2 << 16) | (b3 << 24);
  }
  u8* drow = xT + ((((long)(b << 8) + tid) << 12)) + ((r0 >> 7) << 7);
  const int cb = (r0 & 127) >> 3, key = tid & 15;
  *(uint2*)(drow + ((cb ^ key) << 3)) = *(uint2*)(ob);
  *(uint2*)(drow + (((cb + 1) ^ key) << 3)) = *(uint2*)(ob + 2);
}

// ---------------- main fused kernel: producer/consumer wave specialization ----------------
// 256 blocks x 1024 thr (16 waves, 4/SIMD, 1 block/CU). Block = (batch, 64 Q rows).
// K-tile 128, 32 iters, ONE barrier/iter.
// QK waves (0-7): DMA K(it+1) -> dbuf LDS; mm1(it) (16x16x32 fp8, S^T, Q from static LDS tile);
//                 exp2 -> P(it) dbuf LDS; rowsum partials.
// PV waves (8-15): V(it) -> regs (dbuf); mm2(it-1) (32x32x16 fp8) from P(it-1) + vf(it-1).
__global__ __launch_bounds__(1024, 4) void tpe_main(
    const u8* __restrict__ xbf, const u8* __restrict__ xT,
    const float* __restrict__ sqh,
    const float* __restrict__ x, float* __restrict__ out) {
  __shared__ u8 Qs[16384];       // static Q tile (rows q0..q0+63 of xbf, swizzle preserved)
  __shared__ u8 Kt[2][32768];    // K tile dbuf, 128 rows x 256 B (row-swizzled)
  __shared__ u8 Ps[2][64 * PSTR];
  __shared__ float lred[8][64];
  __shared__ float linv[64];

  const int tid = threadIdx.x;
  const int w = tid >> 6;
  const int lane = tid & 63;
  const int l15 = lane & 15, l31 = lane & 31;
  const int q4 = lane >> 4;   // 0..3
  const int q2 = lane >> 5;   // 0..1

  // XCD pinning: batch -> XCD pair (2 MB fp8 set stays L2-hot)
  const int blk = blockIdx.x;
  const int b = (blk & 7) >> 1;
  const int qt = ((blk >> 3) << 1) | (blk & 1);
  const int q0 = qt << 6;
  const long bL = (long)b * LL;

  const u8* kbat = xbf + (bL << 8);
  // PV: V segment for this wave's O columns d = 32*(w&7) + l31 (key = d&15)
  const u8* vseg = xT + (((long)(b << 8) + 32 * (w & 7) + l31) << 12);
  const int vkey = l31 & 15;

  // prologue DMA: Q tile (all 16 waves) + K tile 0 (QK waves)
  dma16(kbat + (q0 << 8) + tid * 16, Qs + tid * 16);
  if (w < 8) {
    #pragma unroll
    for (int c = 0; c < 4; ++c) {
      int off = c * 8192 + tid * 16;
      dma16(kbat + off, Kt[0] + off);
    }
  }

  float qa[4];
  if (w < 8) {
    #pragma unroll
    for (int t = 0; t < 4; ++t) qa[t] = sqh[bL + q0 + 16 * t + l15];
  }
  f32x16 oacc[2];
  #pragma unroll
  for (int rb = 0; rb < 2; ++rb)
    #pragma unroll
    for (int k = 0; k < 16; ++k) oacc[rb][k] = 0.f;
  float rsacc[4] = {0.f, 0.f, 0.f, 0.f};
  uint2 vfA[8], vfB[8];

  __syncthreads();   // Qs + Kt[0] resident

#define TPE_ITER(IT, KCUR, KNXT, PCUR, PPREV, VFN, VFC)                                     \
  {                                                                                         \
    if (w < 8) {                                                                            \
      if ((IT) < 31) { /* DMA K(it+1): full iteration of flight before the barrier */       \
        const u8* ks = kbat + ((long)((IT) + 1) << 15);                                     \
        _Pragma("unroll")                                                                   \
        for (int c = 0; c < 4; ++c) {                                                       \
          int off = c * 8192 + tid * 16;                                                    \
          dma16(ks + off, (KNXT) + off);                                                    \
        }                                                                                   \
      }                                                                                     \
      float4 skv4 = *(const float4*)(sqh + bL + ((IT) << 7) + 16 * w + 4 * q4);             \
      f32x4 sacc[4];                                                                        \
      _Pragma("unroll")                                                                     \
      for (int t = 0; t < 4; ++t) {                                                         \
        sacc[t][0] = 0.f; sacc[t][1] = 0.f; sacc[t][2] = 0.f; sacc[t][3] = 0.f;             \
      }                                                                                     \
      const int krow = 16 * w + l15;                                                        \
      const int kkey = krow & 31;                                                           \
      const u8* kb2 = (KCUR) + krow * 256;                                                  \
      _Pragma("unroll")                                                                     \
      for (int s = 0; s < 8; ++s) { /* mm1: 32-MFMA run, 4 chains, Q from LDS */            \
        long av = *(const long*)(kb2 + (((q4 + 4 * s) ^ kkey) << 3));                       \
        _Pragma("unroll")                                                                   \
        for (int t = 0; t < 4; ++t) {                                                       \
          const int qrow = 16 * t + l15;                                                    \
          long qv = *(const long*)(Qs + qrow * 256 + (((q4 + 4 * s) ^ (qrow & 31)) << 3));  \
          sacc[t] = __builtin_amdgcn_mfma_f32_16x16x32_fp8_fp8(av, qv, sacc[t], 0, 0, 0);   \
        }                                                                                   \
      }                                                                                     \
      _Pragma("unroll") /* P = exp2(min(0, g*GS2 + qa + skv)) -> LDS fp8 */                 \
      for (int t = 0; t < 4; ++t) { /* lane: P[i=16t+l15][j=16w+4q4+0..3] */                \
        float p0 = __builtin_amdgcn_exp2f(fminf(fmaf(sacc[t][0], GSCALE2, qa[t] + skv4.x), 0.f)); \
        float p1 = __builtin_amdgcn_exp2f(fminf(fmaf(sacc[t][1], GSCALE2, qa[t] + skv4.y), 0.f)); \
        float p2 = __builtin_amdgcn_exp2f(fminf(fmaf(sacc[t][2], GSCALE2, qa[t] + skv4.z), 0.f)); \
        float p3 = __builtin_amdgcn_exp2f(fminf(fmaf(sacc[t][3], GSCALE2, qa[t] + skv4.w), 0.f)); \
        rsacc[t] += (p0 + p1) + (p2 + p3);                                                  \
        int pk = __builtin_amdgcn_cvt_pk_fp8_f32(p0, p1, 0, false);                         \
        pk = __builtin_amdgcn_cvt_pk_fp8_f32(p2, p3, pk, true);                             \
        *(int*)((PCUR) + (16 * t + l15) * PSTR + 16 * w + 4 * q4) = pk;                     \
      }                                                                                     \
    } else {                                                                                \
      const int j0 = (IT) << 7;                                                             \
      _Pragma("unroll") /* V(it) -> regs; fly during mm2 */                                 \
      for (int s = 0; s < 8; ++s)                                                           \
        VFN[s] = *(const uint2*)(vseg + j0 + (((2 * s + q2) ^ vkey) << 3));                 \
      if ((IT) != 0) { /* mm2 on tile it-1: A = P(it-1) LDS, B = vf(it-1) regs */           \
        _Pragma("unroll")                                                                   \
        for (int s = 0; s < 8; ++s) {                                                       \
          long a0 = *(const long*)((PPREV) + l31 * PSTR + 16 * s + 8 * q2);                 \
          long a1 = *(const long*)((PPREV) + (32 + l31) * PSTR + 16 * s + 8 * q2);          \
          long bv = LCAST(VFC[s]);                                                          \
          oacc[0] = __builtin_amdgcn_mfma_f32_32x32x16_fp8_fp8(a0, bv, oacc[0], 0, 0, 0);   \
          oacc[1] = __builtin_amdgcn_mfma_f32_32x32x16_fp8_fp8(a1, bv, oacc[1], 0, 0, 0);   \
        }                                                                                   \
      }                                                                                     \
    }                                                                                       \
    __syncthreads(); /* ONE barrier: P(it) visible, K(it+1)+vf(it) drained */               \
  }

  for (int it2 = 0; it2 < 16; ++it2) {
    TPE_ITER(2 * it2,     Kt[0], Kt[1], Ps[0], Ps[1], vfA, vfB)
    TPE_ITER(2 * it2 + 1, Kt[1], Kt[0], Ps[1], Ps[0], vfB, vfA)
  }
#undef TPE_ITER

  // ---- final mm2 (tile 31: P = Ps[1], V = vfB) ----
  if (w >= 8) {
    #pragma unroll
    for (int s = 0; s < 8; ++s) {
      long a0 = *(const long*)(Ps[1] + l31 * PSTR + 16 * s + 8 * q2);
      long a1 = *(const long*)(Ps[1] + (32 + l31) * PSTR + 16 * s + 8 * q2);
      long bv = LCAST(vfB[s]);
      oacc[0] = __builtin_amdgcn_mfma_f32_32x32x16_fp8_fp8(a0, bv, oacc[0], 0, 0, 0);
      oacc[1] = __builtin_amdgcn_mfma_f32_32x32x16_fp8_fp8(a1, bv, oacc[1], 0, 0, 0);
    }
  }

  // ---- epilogue: rowsum reduce (QK waves); out-write (PV waves) ----
  if (w < 8) {
    #pragma unroll
    for (int t = 0; t < 4; ++t) {
      float r = rsacc[t];
      r += __shfl_xor(r, 16);
      r += __shfl_xor(r, 32);
      if (lane < 16) lred[w][16 * t + l15] = r;
    }
  }
  __syncthreads();
  if (tid < 64) {
    float s = 0.f;
    #pragma unroll
    for (int ww = 0; ww < 8; ++ww) s += lred[ww][tid];
    linv[tid] = 0.0625f / s;   // 1/16 undoes V pre-scale
  }
  __syncthreads();
  if (w >= 8) {
    const int col = 32 * (w & 7) + l31;
    const float freq = __expf((float)(col & ~1) * FREQC);
    #pragma unroll
    for (int rb = 0; rb < 2; ++rb) {
      #pragma unroll
      for (int reg = 0; reg < 16; ++reg) {
        int row = 32 * rb + 4 * q2 + (reg & 3) + 8 * (reg >> 2);
        int l = q0 + row;
        float ang = (float)l * freq;
        float pv = (col & 1) ? __cosf(ang) : __sinf(ang);
        long off = ((bL + l) << 8) + col;
        out[off] = oacc[rb][reg] * linv[row] + x[off] + pv;
      }
    }
  }
}

extern "C" void kernel_launch(void* const* d_in, const int* in_sizes, int n_in,
                              void* d_out, int out_size, void* d_ws, size_t ws_size,
                              hipStream_t stream) {
  const float* x = (const float*)d_in[0];
  float* out = (float*)d_out;
  char* ws = (char*)d_ws;
  u8* xbf = (u8*)ws;                       // 4,194,304 B  (fp8 x, swizzled rows)
  u8* xT = (u8*)(ws + 4194304);            // 4,194,304 B  (fp8 x^T, swizzled segments)
  float* sq = (float*)(ws + 8388608);      //    65,536 B  (-0.5*log2e*||x||^2)
  prep1<<<1024, 256, 0, stream>>>(x, xbf, xT, sq);
  tpe_main<<<256, 1024, 0, stream>>>(xbf, xT, sq, x, out);
}